// Round 6
// baseline (1851.032 us; speedup 1.0000x reference)
//
#include <hip/hip_runtime.h>
#include <hip/hip_bf16.h>
#include <cstddef>
#include <cstdint>

// Problem constants (match reference)
constexpr int NB    = 16;       // batch
constexpr int NN    = 2000;     // nodes per batch
constexpr int TH    = 24;       // T_HIST
constexpr int TF    = 24;       // T_FCST
constexpr int HID   = 64;
constexpr int NF    = 8;        // features
constexpr int NODES = NB * NN;      // 32000
constexpr int HNODE = NODES / 2;    // 16000 (2-node register blocking)
constexpr int ETOT  = NODES * 32;   // 1,024,000 edges
constexpr int TT    = TH + TF;      // 48

__device__ __forceinline__ float sigmoidf_(float x) { return 1.f / (1.f + __expf(-x)); }
__device__ __forceinline__ float tanhf_(float x) {
    float e = __expf(2.f * x);
    return 1.f - 2.f / (e + 1.f);   // safe at +/-inf
}

__device__ __forceinline__ uint16_t f2bf(float x) {
    __hip_bfloat16 b = __float2bfloat16(x);
    uint16_t u; __builtin_memcpy(&u, &b, 2); return u;
}

// GRU grid: 512 blocks. jg-blocks of one chunk share (id & 7) => same XCD.
// decode: jg = (id>>3)&7 ; c = (id&7) + 8*(id>>6), c in [0,64)
__device__ __forceinline__ void swz2(int id, int& c, int& jg) {
    jg = (id >> 3) & 7;
    c  = (id & 7) + 8 * (id >> 6);
}

// ---------------- setup kernels ----------------
__global__ void k_init(float* __restrict__ hA, float* __restrict__ dis) {
    int i = blockIdx.x * blockDim.x + threadIdx.x;
    if (i < HID * NODES) hA[i] = 0.f;
    if (i < NODES) dis[i] = 0.f;
}

__global__ void k_deg(const int* __restrict__ ei, float* __restrict__ deg) {
    int e = blockIdx.x * blockDim.x + threadIdx.x;
    if (e < ETOT) atomicAdd(&deg[ei[ETOT + e]], 1.0f);
}

// single block of 256: exclusive prefix sum of (int)degf -> row0[NODES+1], zero cnt
__global__ __launch_bounds__(256) void k_scan(const float* __restrict__ degf,
                                              int* __restrict__ row0,
                                              int* __restrict__ cnt)
{
    __shared__ int part[256];
    const int tid = threadIdx.x;
    const int per = NODES / 256;   // 125
    const int base = tid * per;
    int s = 0;
    for (int i = 0; i < per; i++) s += (int)degf[base + i];
    part[tid] = s;
    __syncthreads();
    for (int off = 1; off < 256; off <<= 1) {
        int v = (tid >= off) ? part[tid - off] : 0;
        __syncthreads();
        part[tid] += v;
        __syncthreads();
    }
    int run = (tid == 0) ? 0 : part[tid - 1];
    for (int i = 0; i < per; i++) {
        row0[base + i] = run;
        cnt[base + i]  = 0;
        run += (int)degf[base + i];
    }
    if (tid == 255) row0[NODES] = run;
}

__global__ void k_dis(float* __restrict__ dis) {
    int i = blockIdx.x * blockDim.x + threadIdx.x;
    if (i < NODES) {
        float d = dis[i];
        dis[i] = (d > 0.f) ? rsqrtf(fmaxf(d, 1.f)) : 0.f;
    }
}

// build dst-CSR with packed {src, norm} 8B records; norm computed inline
__global__ void k_fill(const int* __restrict__ ei, const float* __restrict__ dis,
                       const int* __restrict__ row0, int* __restrict__ cnt,
                       int2* __restrict__ edge8)
{
    int e = blockIdx.x * blockDim.x + threadIdx.x;
    if (e < ETOT) {
        int s = ei[e];
        int d = ei[ETOT + e];
        float nv = -(dis[s] * dis[d]);
        int p = atomicAdd(&cnt[d], 1);
        edge8[row0[d] + p] = make_int2(s, __float_as_int(nv));
    }
}

// transpose w_hh (192x64, row-major) -> Wt (64x192, k-major)
__global__ void k_prep(const float* __restrict__ whe, const float* __restrict__ whd,
                       float* __restrict__ Wte, float* __restrict__ Wtd) {
    int i = blockIdx.x * blockDim.x + threadIdx.x;   // i = k*192 + g
    if (i < 192 * 64) {
        int k = i / 192, g = i - k * 192;
        Wte[i] = whe[g * 64 + k];
        Wtd[i] = whd[g * 64 + k];
    }
}

// ---------------- encoder step ----------------
// h layout: float4-packed k-groups  h4[kq][node]. Thread = 2 nodes (n0, n0+16000),
// 8 output channels each. Weights wave-uniform, amortized over 2 nodes.
__global__ __launch_bounds__(256) void k_enc(
    const float* __restrict__ pm,
    const float* __restrict__ w_ih, const float* __restrict__ Wt,
    const float* __restrict__ b_ih, const float* __restrict__ b_hh,
    const float* __restrict__ fc_w, const float* __restrict__ fc_b,
    const float* __restrict__ h_in, float* __restrict__ h_out,
    __hip_bfloat16* __restrict__ Hb, int t)
{
    int c, jg;
    swz2(blockIdx.x, c, jg);
    const int n0 = c * 256 + threadIdx.x;
    if (n0 >= HNODE) return;
    const int n1 = n0 + HNODE;
    const int j0 = jg * 8;

    float ar0[8], az0[8], an0[8], ar1[8], az1[8], an1[8];
    #pragma unroll
    for (int m = 0; m < 8; m++) {
        ar0[m] = ar1[m] = b_hh[j0 + m];
        az0[m] = az1[m] = b_hh[64 + j0 + m];
        an0[m] = an1[m] = b_hh[128 + j0 + m];
    }
    float axn0 = 0.f, axn1 = 0.f;
    const float4* h4 = (const float4*)h_in;
    #pragma unroll 4
    for (int kq = 0; kq < 16; kq++) {
        const float4 hv0 = h4[(size_t)kq * NODES + n0];
        const float4 hv1 = h4[(size_t)kq * NODES + n1];
        const float hk0[4] = {hv0.x, hv0.y, hv0.z, hv0.w};
        const float hk1[4] = {hv1.x, hv1.y, hv1.z, hv1.w};
        #pragma unroll
        for (int u = 0; u < 4; u++) {
            const int k = kq * 4 + u;
            const float* w = Wt + k * 192 + j0;
            #pragma unroll
            for (int m = 0; m < 8; m++) {
                const float wr = w[m], wz = w[64 + m], wn = w[128 + m];
                ar0[m] = fmaf(wr, hk0[u], ar0[m]);
                az0[m] = fmaf(wz, hk0[u], az0[m]);
                an0[m] = fmaf(wn, hk0[u], an0[m]);
                ar1[m] = fmaf(wr, hk1[u], ar1[m]);
                az1[m] = fmaf(wz, hk1[u], az1[m]);
                an1[m] = fmaf(wn, hk1[u], an1[m]);
            }
            const float wf = fc_w[k];
            axn0 = fmaf(wf, hk0[u], axn0);
            axn1 = fmaf(wf, hk1[u], axn1);
        }
    }
    const float xn0 = (t > 0) ? (axn0 + fc_b[0]) : 0.f;
    const float xn1 = (t > 0) ? (axn1 + fc_b[0]) : 0.f;

    const int b0 = n0 / NN, bn0 = n0 - b0 * NN;
    const int b1 = n1 / NN, bn1 = n1 - b1 * NN;
    const float pmv0 = pm[(b0 * TH + t) * NN + bn0];
    const float pmv1 = pm[(b1 * TH + t) * NN + bn1];

    const float4 ho00 = h4[(size_t)(2 * jg)     * NODES + n0];
    const float4 ho01 = h4[(size_t)(2 * jg + 1) * NODES + n0];
    const float4 ho10 = h4[(size_t)(2 * jg)     * NODES + n1];
    const float4 ho11 = h4[(size_t)(2 * jg + 1) * NODES + n1];
    const float hold0[8] = {ho00.x, ho00.y, ho00.z, ho00.w, ho01.x, ho01.y, ho01.z, ho01.w};
    const float hold1[8] = {ho10.x, ho10.y, ho10.z, ho10.w, ho11.x, ho11.y, ho11.z, ho11.w};
    float hn0[8], hn1[8];
    #pragma unroll
    for (int m = 0; m < 8; m++) {
        const int j = j0 + m;
        const float wi0 = w_ih[2 * j],         wi1 = w_ih[2 * j + 1];
        const float wz0 = w_ih[2 * (64 + j)],  wz1 = w_ih[2 * (64 + j) + 1];
        const float wn0 = w_ih[2 * (128 + j)], wn1 = w_ih[2 * (128 + j) + 1];
        const float br = b_ih[j], bz = b_ih[64 + j], bn = b_ih[128 + j];
        {
            float gr = br + wi0 * xn0 + wi1 * pmv0;
            float gz = bz + wz0 * xn0 + wz1 * pmv0;
            float gn = bn + wn0 * xn0 + wn1 * pmv0;
            float r   = sigmoidf_(gr + ar0[m]);
            float z   = sigmoidf_(gz + az0[m]);
            float nn_ = tanhf_(gn + r * an0[m]);
            hn0[m] = (1.f - z) * nn_ + z * hold0[m];
        }
        {
            float gr = br + wi0 * xn1 + wi1 * pmv1;
            float gz = bz + wz0 * xn1 + wz1 * pmv1;
            float gn = bn + wn0 * xn1 + wn1 * pmv1;
            float r   = sigmoidf_(gr + ar1[m]);
            float z   = sigmoidf_(gz + az1[m]);
            float nn_ = tanhf_(gn + r * an1[m]);
            hn1[m] = (1.f - z) * nn_ + z * hold1[m];
        }
    }
    float4* o4 = (float4*)h_out;
    o4[(size_t)(2 * jg)     * NODES + n0] = make_float4(hn0[0], hn0[1], hn0[2], hn0[3]);
    o4[(size_t)(2 * jg + 1) * NODES + n0] = make_float4(hn0[4], hn0[5], hn0[6], hn0[7]);
    o4[(size_t)(2 * jg)     * NODES + n1] = make_float4(hn1[0], hn1[1], hn1[2], hn1[3]);
    o4[(size_t)(2 * jg + 1) * NODES + n1] = make_float4(hn1[4], hn1[5], hn1[6], hn1[7]);

    *(uint4*)(Hb + (size_t)n0 * (TH * HID) + t * HID + j0) = make_uint4(
        (uint32_t)f2bf(hn0[0]) | ((uint32_t)f2bf(hn0[1]) << 16),
        (uint32_t)f2bf(hn0[2]) | ((uint32_t)f2bf(hn0[3]) << 16),
        (uint32_t)f2bf(hn0[4]) | ((uint32_t)f2bf(hn0[5]) << 16),
        (uint32_t)f2bf(hn0[6]) | ((uint32_t)f2bf(hn0[7]) << 16));
    *(uint4*)(Hb + (size_t)n1 * (TH * HID) + t * HID + j0) = make_uint4(
        (uint32_t)f2bf(hn1[0]) | ((uint32_t)f2bf(hn1[1]) << 16),
        (uint32_t)f2bf(hn1[2]) | ((uint32_t)f2bf(hn1[3]) << 16),
        (uint32_t)f2bf(hn1[4]) | ((uint32_t)f2bf(hn1[5]) << 16),
        (uint32_t)f2bf(hn1[6]) | ((uint32_t)f2bf(hn1[7]) << 16));
}

// after encoder: xn0 = fc(h_final); y1 for decoder t=0
__global__ __launch_bounds__(256) void k_fc(
    const float* __restrict__ h_in, const float* __restrict__ fc_w,
    const float* __restrict__ fc_b, const float* __restrict__ feat,
    const float* __restrict__ cw1, float* __restrict__ xn_buf,
    float* __restrict__ y1)
{
    const int node = blockIdx.x * 256 + threadIdx.x;
    if (node >= NODES) return;
    const float4* h4 = (const float4*)h_in;
    const float4* w4 = (const float4*)fc_w;
    float acc = fc_b[0];
    #pragma unroll 8
    for (int kq = 0; kq < 16; kq++) {
        const float4 v = h4[(size_t)kq * NODES + node];
        const float4 w = w4[kq];
        acc = fmaf(w.x, v.x, acc);
        acc = fmaf(w.y, v.y, acc);
        acc = fmaf(w.z, v.z, acc);
        acc = fmaf(w.w, v.w, acc);
    }
    xn_buf[node] = acc;
    const int b = node / NN, n = node - b * NN;
    const float* fp = feat + ((size_t)(b * TT + TH) * NN + n) * NF;
    float yy = acc * cw1[0];
    #pragma unroll
    for (int c = 0; c < NF; c++) yy += fp[c] * cw1[1 + c];
    y1[node] = yy;
}

// ---------------- decoder kernels ----------------
// CSR gather: 4 lanes per node, packed 8B edge records.
__global__ __launch_bounds__(256) void k_gather(
    const int* __restrict__ row0, const int2* __restrict__ edge8,
    const float* __restrict__ y1, float* __restrict__ tx)
{
    const int tid  = blockIdx.x * 256 + threadIdx.x;
    const int node = tid >> 2;
    const int q    = tid & 3;
    if (node >= NODES) return;
    const int beg = row0[node], end = row0[node + 1];
    float acc = 0.f;
    for (int i = beg + q; i < end; i += 4) {
        const int2 e = edge8[i];
        acc = fmaf(__int_as_float(e.y), y1[e.x], acc);
    }
    acc += __shfl_xor(acc, 1, 64);
    acc += __shfl_xor(acc, 2, 64);
    if (q == 0) tx[node] = acc;
}

__global__ __launch_bounds__(256) void k_dgru(
    const float* __restrict__ feat,
    const float* __restrict__ w_ih, const float* __restrict__ Wt,
    const float* __restrict__ b_ih, const float* __restrict__ b_hh,
    const float* __restrict__ w0, const float* __restrict__ cb,
    const float* __restrict__ xn_buf, const float* __restrict__ tx,
    const float* __restrict__ h_in, float* __restrict__ h_out,
    float* __restrict__ h_nm, int t)
{
    int c, jg;
    swz2(blockIdx.x, c, jg);
    const int n0 = c * 256 + threadIdx.x;
    if (n0 >= HNODE) return;
    const int n1 = n0 + HNODE;
    const int j0 = jg * 8;

    float ar0[8], az0[8], an0[8], ar1[8], az1[8], an1[8];
    #pragma unroll
    for (int m = 0; m < 8; m++) {
        ar0[m] = ar1[m] = b_hh[j0 + m];
        az0[m] = az1[m] = b_hh[64 + j0 + m];
        an0[m] = an1[m] = b_hh[128 + j0 + m];
    }
    const float4* h4 = (const float4*)h_in;
    #pragma unroll 4
    for (int kq = 0; kq < 16; kq++) {
        const float4 hv0 = h4[(size_t)kq * NODES + n0];
        const float4 hv1 = h4[(size_t)kq * NODES + n1];
        const float hk0[4] = {hv0.x, hv0.y, hv0.z, hv0.w};
        const float hk1[4] = {hv1.x, hv1.y, hv1.z, hv1.w};
        #pragma unroll
        for (int u = 0; u < 4; u++) {
            const int k = kq * 4 + u;
            const float* w = Wt + k * 192 + j0;
            #pragma unroll
            for (int m = 0; m < 8; m++) {
                const float wr = w[m], wz = w[64 + m], wn = w[128 + m];
                ar0[m] = fmaf(wr, hk0[u], ar0[m]);
                az0[m] = fmaf(wz, hk0[u], az0[m]);
                an0[m] = fmaf(wn, hk0[u], an0[m]);
                ar1[m] = fmaf(wr, hk1[u], ar1[m]);
                az1[m] = fmaf(wz, hk1[u], az1[m]);
                an1[m] = fmaf(wn, hk1[u], an1[m]);
            }
        }
    }

    const int b0 = n0 / NN, bn0 = n0 - b0 * NN;
    const int b1 = n1 / NN, bn1 = n1 - b1 * NN;
    const float xv0 = xn_buf[n0], xv1 = xn_buf[n1];
    float f0[NF], f1[NF];
    const float* fp0 = feat + ((size_t)(b0 * TT + TH + t) * NN + bn0) * NF;
    const float* fp1 = feat + ((size_t)(b1 * TT + TH + t) * NN + bn1) * NF;
    #pragma unroll
    for (int q = 0; q < NF; q++) { f0[q] = fp0[q]; f1[q] = fp1[q]; }

    float xw0 = xv0 * w0[0], xw1 = xv1 * w0[0];
    #pragma unroll
    for (int q = 0; q < NF; q++) {
        xw0 = fmaf(f0[q], w0[1 + q], xw0);
        xw1 = fmaf(f1[q], w0[1 + q], xw1);
    }
    const float xg0 = sigmoidf_(xw0 + tx[n0] + cb[0]);
    const float xg1 = sigmoidf_(xw1 + tx[n1] + cb[0]);

    const float4 ho00 = h4[(size_t)(2 * jg)     * NODES + n0];
    const float4 ho01 = h4[(size_t)(2 * jg + 1) * NODES + n0];
    const float4 ho10 = h4[(size_t)(2 * jg)     * NODES + n1];
    const float4 ho11 = h4[(size_t)(2 * jg + 1) * NODES + n1];
    const float hold0[8] = {ho00.x, ho00.y, ho00.z, ho00.w, ho01.x, ho01.y, ho01.z, ho01.w};
    const float hold1[8] = {ho10.x, ho10.y, ho10.z, ho10.w, ho11.x, ho11.y, ho11.z, ho11.w};
    float hn0[8], hn1[8];
    #pragma unroll
    for (int m = 0; m < 8; m++) {
        const int j = j0 + m;
        const float* ir  = w_ih + j * 10;
        const float* iz  = w_ih + (64 + j) * 10;
        const float* in_ = w_ih + (128 + j) * 10;
        const float br = b_ih[j], bz = b_ih[64 + j], bn = b_ih[128 + j];
        {
            float gr = br + ir[0] * xv0;
            float gz = bz + iz[0] * xv0;
            float gn = bn + in_[0] * xv0;
            #pragma unroll
            for (int q = 0; q < NF; q++) {
                gr = fmaf(ir[1 + q],  f0[q], gr);
                gz = fmaf(iz[1 + q],  f0[q], gz);
                gn = fmaf(in_[1 + q], f0[q], gn);
            }
            gr = fmaf(ir[9],  xg0, gr);
            gz = fmaf(iz[9],  xg0, gz);
            gn = fmaf(in_[9], xg0, gn);
            float r   = sigmoidf_(gr + ar0[m]);
            float z   = sigmoidf_(gz + az0[m]);
            float nn_ = tanhf_(gn + r * an0[m]);
            hn0[m] = (1.f - z) * nn_ + z * hold0[m];
        }
        {
            float gr = br + ir[0] * xv1;
            float gz = bz + iz[0] * xv1;
            float gn = bn + in_[0] * xv1;
            #pragma unroll
            for (int q = 0; q < NF; q++) {
                gr = fmaf(ir[1 + q],  f1[q], gr);
                gz = fmaf(iz[1 + q],  f1[q], gz);
                gn = fmaf(in_[1 + q], f1[q], gn);
            }
            gr = fmaf(ir[9],  xg1, gr);
            gz = fmaf(iz[9],  xg1, gz);
            gn = fmaf(in_[9], xg1, gn);
            float r   = sigmoidf_(gr + ar1[m]);
            float z   = sigmoidf_(gz + az1[m]);
            float nn_ = tanhf_(gn + r * an1[m]);
            hn1[m] = (1.f - z) * nn_ + z * hold1[m];
        }
    }
    float4* o4 = (float4*)h_out;
    o4[(size_t)(2 * jg)     * NODES + n0] = make_float4(hn0[0], hn0[1], hn0[2], hn0[3]);
    o4[(size_t)(2 * jg + 1) * NODES + n0] = make_float4(hn0[4], hn0[5], hn0[6], hn0[7]);
    o4[(size_t)(2 * jg)     * NODES + n1] = make_float4(hn1[0], hn1[1], hn1[2], hn1[3]);
    o4[(size_t)(2 * jg + 1) * NODES + n1] = make_float4(hn1[4], hn1[5], hn1[6], hn1[7]);
    float4* nm4 = (float4*)h_nm;
    nm4[(size_t)n0 * 16 + 2 * jg]     = make_float4(hn0[0], hn0[1], hn0[2], hn0[3]);
    nm4[(size_t)n0 * 16 + 2 * jg + 1] = make_float4(hn0[4], hn0[5], hn0[6], hn0[7]);
    nm4[(size_t)n1 * 16 + 2 * jg]     = make_float4(hn1[0], hn1[1], hn1[2], hn1[3]);
    nm4[(size_t)n1 * 16 + 2 * jg + 1] = make_float4(hn1[4], hn1[5], hn1[6], hn1[7]);
}

// attention + out-projection + y1 prep for next step. Wave per node.
__global__ __launch_bounds__(256) void k_attn(
    const __hip_bfloat16* __restrict__ Hb, const float* __restrict__ h_nm,
    const float* __restrict__ out_w, const float* __restrict__ out_b,
    const float* __restrict__ feat, const float* __restrict__ cw1,
    float* __restrict__ xn_buf, float* __restrict__ y1,
    float* __restrict__ out, int t)
{
    const int wid  = threadIdx.x >> 6;
    const int lane = threadIdx.x & 63;
    const int node = blockIdx.x * 4 + wid;
    if (node >= NODES) return;
    const int d0 = (lane & 7) * 8;     // channel block this lane owns

    const float hj = h_nm[(size_t)node * HID + lane];
    float hval[8];
    #pragma unroll
    for (int q = 0; q < 8; q++) hval[q] = __shfl(hj, d0 + q, 64);

    const uint4* Hrow = (const uint4*)(Hb + (size_t)node * (TH * HID));
    float Hf[3][8];
    float er[3];
    #pragma unroll
    for (int R = 0; R < 3; R++) {
        const uint4 v = Hrow[R * 64 + lane];
        const uint32_t u0 = v.x, u1 = v.y, u2 = v.z, u3 = v.w;
        Hf[R][0] = __uint_as_float(u0 << 16);
        Hf[R][1] = __uint_as_float(u0 & 0xffff0000u);
        Hf[R][2] = __uint_as_float(u1 << 16);
        Hf[R][3] = __uint_as_float(u1 & 0xffff0000u);
        Hf[R][4] = __uint_as_float(u2 << 16);
        Hf[R][5] = __uint_as_float(u2 & 0xffff0000u);
        Hf[R][6] = __uint_as_float(u3 << 16);
        Hf[R][7] = __uint_as_float(u3 & 0xffff0000u);
        float part = 0.f;
        #pragma unroll
        for (int q = 0; q < 8; q++) part = fmaf(Hf[R][q], hval[q], part);
        part += __shfl_xor(part, 1, 64);
        part += __shfl_xor(part, 2, 64);
        part += __shfl_xor(part, 4, 64);
        er[R] = part;
    }

    float m = fmaxf(fmaxf(er[0], er[1]), er[2]);
    m = fmaxf(m, __shfl_xor(m, 8, 64));
    m = fmaxf(m, __shfl_xor(m, 16, 64));
    m = fmaxf(m, __shfl_xor(m, 32, 64));

    float w0_ = __expf(er[0] - m);
    float w1_ = __expf(er[1] - m);
    float w2_ = __expf(er[2] - m);
    float s = w0_ + w1_ + w2_;
    s += __shfl_xor(s, 8, 64);
    s += __shfl_xor(s, 16, 64);
    s += __shfl_xor(s, 32, 64);
    const float rs = 1.f / s;

    float aq[8];
    #pragma unroll
    for (int q = 0; q < 8; q++) {
        float a = w0_ * Hf[0][q];
        a = fmaf(w1_, Hf[1][q], a);
        a = fmaf(w2_, Hf[2][q], a);
        a += __shfl_xor(a, 8, 64);
        a += __shfl_xor(a, 16, 64);
        a += __shfl_xor(a, 32, 64);
        aq[q] = a * rs;
    }

    float part = 0.f;
    #pragma unroll
    for (int q = 0; q < 8; q++) {
        part = fmaf(out_w[d0 + q],       aq[q],   part);
        part = fmaf(out_w[HID + d0 + q], hval[q], part);
    }
    part += __shfl_xor(part, 1, 64);
    part += __shfl_xor(part, 2, 64);
    part += __shfl_xor(part, 4, 64);
    const float xnew = part + out_b[0];

    if (lane == 0) {
        const int b = node / NN, n = node - b * NN;
        out[(b * TF + t) * NN + n] = xnew;
        xn_buf[node] = xnew;
        if (t + 1 < TF) {
            const float* fp = feat + ((size_t)(b * TT + TH + t + 1) * NN + n) * NF;
            float yy = xnew * cw1[0];
            #pragma unroll
            for (int c = 0; c < NF; c++) yy += fp[c] * cw1[1 + c];
            y1[node] = yy;
        }
    }
}

// ---------------- host launch ----------------
extern "C" void kernel_launch(void* const* d_in, const int* in_sizes, int n_in,
                              void* d_out, int out_size, void* d_ws, size_t ws_size,
                              hipStream_t stream)
{
    const float* pm     = (const float*)d_in[0];
    const float* feat   = (const float*)d_in[1];
    const int*   ei     = (const int*)d_in[2];
    const float* w_ih_e = (const float*)d_in[3];
    const float* w_hh_e = (const float*)d_in[4];
    const float* b_ih_e = (const float*)d_in[5];
    const float* b_hh_e = (const float*)d_in[6];
    const float* fc_w   = (const float*)d_in[7];
    const float* fc_b   = (const float*)d_in[8];
    const float* cw0    = (const float*)d_in[9];
    const float* cw1    = (const float*)d_in[10];
    const float* cb     = (const float*)d_in[11];
    const float* w_ih_d = (const float*)d_in[12];
    const float* w_hh_d = (const float*)d_in[13];
    const float* b_ih_d = (const float*)d_in[14];
    const float* b_hh_d = (const float*)d_in[15];
    const float* out_w  = (const float*)d_in[16];
    const float* out_b  = (const float*)d_in[17];
    float* out = (float*)d_out;

    char* ws = (char*)d_ws;
    size_t off = 0;
    auto alloc = [&](size_t bytes) -> void* {
        void* p = ws + off;
        off += (bytes + 255) & ~(size_t)255;
        return p;
    };
    float* hA   = (float*)alloc(sizeof(float) * HID * NODES);
    float* hB   = (float*)alloc(sizeof(float) * HID * NODES);
    float* h_nm = (float*)alloc(sizeof(float) * HID * NODES);
    __hip_bfloat16* Hb = (__hip_bfloat16*)alloc(sizeof(__hip_bfloat16) * (size_t)NODES * TH * HID);
    float* xn   = (float*)alloc(sizeof(float) * NODES);
    float* dis  = (float*)alloc(sizeof(float) * NODES);
    float* y1   = (float*)alloc(sizeof(float) * NODES);
    float* tx   = (float*)alloc(sizeof(float) * NODES);
    float* WtE  = (float*)alloc(sizeof(float) * 192 * 64);
    float* WtD  = (float*)alloc(sizeof(float) * 192 * 64);
    int*   row0 = (int*)alloc(sizeof(int) * (NODES + 1));
    int*   cnt  = (int*)alloc(sizeof(int) * NODES);
    int2*  edge8 = (int2*)alloc(sizeof(int2) * ETOT);
    if (off > ws_size) return;  // visible failure instead of corruption

    // setup
    k_init<<<(HID * NODES + 255) / 256, 256, 0, stream>>>(hA, dis);
    k_deg<<<(ETOT + 255) / 256, 256, 0, stream>>>(ei, dis);
    k_scan<<<1, 256, 0, stream>>>(dis, row0, cnt);
    k_dis<<<(NODES + 255) / 256, 256, 0, stream>>>(dis);
    k_fill<<<(ETOT + 255) / 256, 256, 0, stream>>>(ei, dis, row0, cnt, edge8);
    k_prep<<<(192 * 64 + 255) / 256, 256, 0, stream>>>(w_hh_e, w_hh_d, WtE, WtD);

    const int gGRU = 512;   // 64 chunk-slots x 8 jgroups, swizzled

    // encoder: ping-pong hA/hB; 24 steps ends back in hA
    for (int t = 0; t < TH; t++) {
        const float* hin = (t & 1) ? hB : hA;
        float* hout      = (t & 1) ? hA : hB;
        k_enc<<<gGRU, 256, 0, stream>>>(pm, w_ih_e, WtE, b_ih_e, b_hh_e,
                                        fc_w, fc_b, hin, hout, Hb, t);
    }
    k_fc<<<NODES / 256, 256, 0, stream>>>(hA, fc_w, fc_b, feat, cw1, xn, y1);

    // decoder
    for (int t = 0; t < TF; t++) {
        const float* hin = (t & 1) ? hB : hA;
        float* hout      = (t & 1) ? hA : hB;
        k_gather<<<(NODES * 4) / 256, 256, 0, stream>>>(row0, edge8, y1, tx);
        k_dgru<<<gGRU, 256, 0, stream>>>(feat, w_ih_d, WtD, b_ih_d, b_hh_d,
                                         cw0, cb, xn, tx, hin, hout, h_nm, t);
        k_attn<<<NODES / 4, 256, 0, stream>>>(Hb, h_nm, out_w, out_b, feat, cw1,
                                              xn, y1, out, t);
    }
}